// Round 18
// baseline (264.543 us; speedup 1.0000x reference)
//
#include <hip/hip_runtime.h>
#include <hip/hip_bf16.h>
#include <hip/hip_fp8.h>

#define U_N 100000
#define I_N 50000
#define E_N 2000000
#define R_N 5
#define C_N (I_N*R_N)   // 250000 combos
#define NBLK_E 7813     // ceil(2000000/256)
#define NBLK_C 1954     // ceil(250000/128)
#define NBUCKC 196      // ceil(100000/512) coarse buckets

typedef __hip_bfloat16 bf16_t;
typedef unsigned short u16;
typedef unsigned char u8;
typedef __attribute__((ext_vector_type(8))) short bf16x8;
typedef __attribute__((ext_vector_type(4))) float f32x4;

__device__ __forceinline__ float blo(unsigned u){ return __uint_as_float(u<<16); }
__device__ __forceinline__ float bhi(unsigned u){ return __uint_as_float(u & 0xffff0000u); }
__device__ __forceinline__ unsigned pkbf(float a, float b){
  __hip_bfloat162 t = __float22bfloat162_rn(float2{a,b});
  union { __hip_bfloat162 h; unsigned u; } cv; cv.h = t; return cv.u;
}
__device__ __forceinline__ u16 f2b(float v){
  union { __hip_bfloat16 h; u16 u; } cv; cv.h = __float2bfloat16(v); return cv.u;
}
__device__ __forceinline__ unsigned ff8(float f){
  __hip_fp8_e4m3 h(f); return (unsigned)h.__x;
}
__device__ __forceinline__ float2 f8x2(u16 h){
  __hip_fp8x2_e4m3 v; v.__x = h; return (float2)v;
}

// ================= CSR build =================
__global__ __launch_bounds__(256) void k_histQ(const int* __restrict__ cols, int* __restrict__ hist_g){
  __shared__ int histI[NBUCKC];
  int t = threadIdx.x, b = blockIdx.x;
  if(t < NBUCKC) histI[t] = 0;
  __syncthreads();
  int e = b*256 + t;
  if(e < E_N) atomicAdd(&histI[cols[e] >> 9], 1);
  __syncthreads();
  if(t < NBUCKC) hist_g[(size_t)b*NBUCKC + t] = histI[t];
}

__global__ __launch_bounds__(256) void k_scanQ(const int* __restrict__ hist_g, int* __restrict__ boff_g,
                                               int* __restrict__ qtot){
  __shared__ int wsum[4];
  int t = threadIdx.x, q = blockIdx.x;
  int lane = t & 63, wv = t >> 6;
  int running = 0;
  for(int c0=0; c0<NBLK_E; c0+=256){
    int b = c0 + t;
    int v = (b < NBLK_E) ? hist_g[(size_t)b*NBUCKC + q] : 0;
    int inc = v;
#pragma unroll
    for(int off=1; off<64; off<<=1){
      int x = __shfl(inc, lane-off);
      if(lane >= off) inc += x;
    }
    if(lane == 63) wsum[wv] = inc;
    __syncthreads();
    int w0=wsum[0], w1=wsum[1], w2=wsum[2], w3=wsum[3];
    int wpre = (wv>0?w0:0) + (wv>1?w1:0) + (wv>2?w2:0);
    if(b < NBLK_E) boff_g[(size_t)b*NBUCKC + q] = running + wpre + inc - v;
    running += w0 + w1 + w2 + w3;
    __syncthreads();
  }
  if(t == 0) qtot[q] = running;
}

__global__ void k_scanT(const int* __restrict__ qtot, int* __restrict__ qbase){
  __shared__ int s[256];
  int t = threadIdx.x;
  int v = (t < NBUCKC) ? qtot[t] : 0;
  s[t] = v; __syncthreads();
  for(int off=1; off<256; off<<=1){
    int x = (t>=off) ? s[t-off] : 0;
    __syncthreads();
    s[t] += x;
    __syncthreads();
  }
  if(t < NBUCKC) qbase[t] = s[t] - v;
  if(t == 255)   qbase[NBUCKC] = s[255];
}

__global__ __launch_bounds__(256) void k_blockq(const int* __restrict__ qbase, int* __restrict__ blockq){
  int b = blockIdx.x*256 + threadIdx.x; if(b >= NBLK_E) return;
  int e = b*256;
  int lo = 0, hi = NBUCKC-1;
  while(lo < hi){ int mid = (lo+hi+1)>>1; if(qbase[mid] <= e) lo = mid; else hi = mid-1; }
  blockq[b] = lo;
}

__global__ __launch_bounds__(256) void k_place2(const int* __restrict__ rows, const int* __restrict__ cols,
                                                const int* __restrict__ rats,
                                                const int* __restrict__ boff_g, const int* __restrict__ qbase,
                                                unsigned* __restrict__ uc2){
  __shared__ int rankI[NBUCKC];
  __shared__ int baseI[NBUCKC];
  int t = threadIdx.x, b = blockIdx.x;
  if(t < NBUCKC){
    rankI[t] = 0;
    baseI[t] = qbase[t] + boff_g[(size_t)b*NBUCKC + t];
  }
  __syncthreads();
  int e = b*256 + t;
  if(e < E_N){
    int u = cols[e];
    int c = rows[e]*5 + rats[e];
    int q = u >> 9;
    int r = atomicAdd(&rankI[q], 1);
    uc2[baseI[q] + r] = ((unsigned)(u & 16383) << 18) | (unsigned)c;
  }
}

// fused fine sort
__global__ __launch_bounds__(256) void k_fine(const unsigned* __restrict__ uc2, const int* __restrict__ qbase,
                                              unsigned* __restrict__ uc3, int* __restrict__ start){
  __shared__ int histv[512];
  __shared__ int s[512];
  __shared__ int fillb[512];
  int t = threadIdx.x, q = blockIdx.x;
  histv[t]=0; histv[t+256]=0; fillb[t]=0; fillb[t+256]=0;
  __syncthreads();
  int r0 = qbase[q], r1 = qbase[q+1];
  for(int j=r0+t; j<r1; j+=256) atomicAdd(&histv[(uc2[j]>>18)&511], 1);
  __syncthreads();
  s[t]=histv[t]; s[t+256]=histv[t+256];
  __syncthreads();
  for(int off=1; off<512; off<<=1){
    int a0 = (t>=off)? s[t-off] : 0;
    int a1 = (t+256>=off)? s[t+256-off] : 0;
    __syncthreads();
    s[t]+=a0; s[t+256]+=a1;
    __syncthreads();
  }
  int e0 = s[t]-histv[t], e1 = s[t+256]-histv[t+256];
  start[q*512+t]     = r0 + e0;
  start[q*512+t+256] = r0 + e1;
  s[t]=e0; s[t+256]=e1;
  __syncthreads();
  for(int j=r0+t; j<r1; j+=256){
    unsigned v = uc2[j];
    int ul = (int)((v>>18)&511);
    int off = atomicAdd(&fillb[ul], 1);
    uc3[r0 + s[ul] + off] = v;
  }
}

// ---------------- tiny precompute ----------------
__global__ void k_ratpart(const float* __restrict__ rf, const float* __restrict__ w1,
                          const float* __restrict__ b1, float* __restrict__ out){
  int t = threadIdx.x; if(t >= R_N*64) return;
  int r = t>>6, d = t&63;
  float acc = b1[d];
  for(int k=0;k<64;k++) acc += rf[r*64 + k] * w1[(64+k)*64 + d];
  out[t] = acc;
}

__global__ __launch_bounds__(256) void k_prepw6(const float* __restrict__ w1, const float* __restrict__ a1,
                                                const float* __restrict__ w2, const float* __restrict__ a2,
                                                const float* __restrict__ ww,
                                                u16* w1t, u16* u1t, u16* w2t, u16* a1t, u16* a2t, u16* wwt){
  int idx = (blockIdx.x & 15)*256 + threadIdx.x;
  int sec = blockIdx.x >> 4;
  int d = idx >> 6, k = idx & 63;
  const float* src; u16* dst; int ko = 0;
  switch(sec){
    case 0: src=w1; dst=w1t; break;
    case 1: src=a1; dst=u1t; ko=64; break;
    case 2: src=w2; dst=w2t; break;
    case 3: src=a1; dst=a1t; break;
    case 4: src=a2; dst=a2t; break;
    default: src=ww; dst=wwt; break;
  }
  dst[idx] = f2b(src[(size_t)(ko+k)*64 + d]);
}

// ---------------- MFMA row-GEMM ----------------
template<bool BIAS>
__global__ __launch_bounds__(256) void k_rowgemm(const float4* __restrict__ in,
                                                 const uint4* __restrict__ wt,
                                                 const float* __restrict__ bias,
                                                 uint4* __restrict__ outp, int n){
  __shared__ uint4 A_u4[2048];
  __shared__ uint4 W_u4[512];
  __shared__ float bsh[64];
  u16* A16 = (u16*)A_u4;
  const int tid = threadIdx.x;
  for(int cid = tid; cid < 512; cid += 256){
    int dd = cid >> 3, ch = cid & 7;
    W_u4[dd*8 + (ch ^ (dd&7))] = wt[cid];
  }
  if(BIAS && tid < 64) bsh[tid] = bias[tid];
  const int base = blockIdx.x*256;
  const int ch = tid & 7;
#pragma unroll
  for(int it=0; it<8; ++it){
    int s = it*32 + (tid>>3);
    int r = base + s;
    uint4 o = {0,0,0,0};
    if(r < n){
      const float4* p = in + (size_t)r*16 + ch*2;
      float4 v0 = p[0], v1 = p[1];
      o.x = pkbf(v0.x, v0.y); o.y = pkbf(v0.z, v0.w);
      o.z = pkbf(v1.x, v1.y); o.w = pkbf(v1.z, v1.w);
    }
    A_u4[s*8 + (ch ^ (s&7))] = o;
  }
  __syncthreads();
  const int l = tid & 63, w = tid >> 6;
  const int lr = l & 15, g = l >> 4;
  bf16x8 bfr[4][2];
#pragma unroll
  for(int nt=0; nt<4; ++nt)
#pragma unroll
    for(int kk=0; kk<2; ++kk){
      int d = nt*16 + lr;
      bfr[nt][kk] = *(const bf16x8*)&W_u4[d*8 + ((kk*4+g) ^ (d&7))];
    }
  float bv[4];
#pragma unroll
  for(int nt=0; nt<4; ++nt) bv[nt] = BIAS ? bsh[nt*16 + lr] : 0.f;
#pragma unroll
  for(int t=0; t<4; ++t){
    int s = w*64 + t*16 + lr;
    bf16x8 af0 = *(const bf16x8*)&A_u4[s*8 + ((0*4+g) ^ (s&7))];
    bf16x8 af1 = *(const bf16x8*)&A_u4[s*8 + ((1*4+g) ^ (s&7))];
    f32x4 acc[4];
#pragma unroll
    for(int nt=0; nt<4; ++nt){
      f32x4 c0 = { bv[nt], bv[nt], bv[nt], bv[nt] };
      c0 = __builtin_amdgcn_mfma_f32_16x16x32_bf16(af0, bfr[nt][0], c0, 0, 0, 0);
      c0 = __builtin_amdgcn_mfma_f32_16x16x32_bf16(af1, bfr[nt][1], c0, 0, 0, 0);
      acc[nt] = c0;
    }
#pragma unroll
    for(int nt=0; nt<4; ++nt){
      int d = nt*16 + lr;
#pragma unroll
      for(int reg=0; reg<4; ++reg){
        int srow = w*64 + t*16 + g*4 + reg;
        A16[srow*64 + ((d>>3)^(srow&7))*8 + (d&7)] = f2b(acc[nt][reg]);
      }
    }
  }
#pragma unroll
  for(int it=0; it<8; ++it){
    int s = w*64 + it*8 + (l>>3);
    int c2 = l & 7;
    int r = base + s;
    if(r < n) outp[(size_t)r*8 + c2] = A_u4[s*8 + (c2 ^ (s&7))];
  }
}

// ---------------- combo: y_o (bf16) + xa1_o (fp8 e4m3) ----------------
__global__ __launch_bounds__(256) void k_combo_mfma(const uint4* __restrict__ itemp,
                                                    const float4* __restrict__ ratp,
                                                    const uint4* __restrict__ w2t_g, const uint4* __restrict__ a1t_g,
                                                    const uint4* __restrict__ wwt_g,
                                                    const float* __restrict__ b2,
                                                    uint4* __restrict__ y_o, u8* __restrict__ xa1_o8){
  __shared__ uint4 A_u4[1024];
  __shared__ uint4 X_u4[1024];
  __shared__ uint4 W2_u4[512];
  __shared__ uint4 A1_u4[512];
  __shared__ uint4 WW_u4[512];
  __shared__ float4 rsh4[80];
  __shared__ float b2sh[64];
  u16* A16 = (u16*)A_u4;
  u16* X16 = (u16*)X_u4;
  const int tid = threadIdx.x;
  for(int cid = tid; cid < 512; cid += 256){
    int dd = cid >> 3, ch = cid & 7;
    W2_u4[dd*8 + (ch ^ (dd&7))] = w2t_g[cid];
    A1_u4[dd*8 + (ch ^ (dd&7))] = a1t_g[cid];
    WW_u4[dd*8 + (ch ^ (dd&7))] = wwt_g[cid];
  }
  if(tid < 80) rsh4[tid] = ratp[tid];
  if(tid < 64) b2sh[tid] = b2[tid];
  __syncthreads();

  const int base = blockIdx.x*128;
  const int ch = tid & 7;
#pragma unroll
  for(int it=0; it<4; ++it){
    int s = it*32 + (tid>>3);
    int cidx = base + s;
    uint4 o = {0,0,0,0};
    if(cidx < C_N){
      int i = cidx/5, r = cidx - i*5;
      uint4 iv = itemp[(size_t)i*8 + ch];
      float4 r0 = rsh4[r*16 + ch*2], r1 = rsh4[r*16 + ch*2 + 1];
      o.x = pkbf(fmaxf(blo(iv.x)+r0.x,0.f), fmaxf(bhi(iv.x)+r0.y,0.f));
      o.y = pkbf(fmaxf(blo(iv.y)+r0.z,0.f), fmaxf(bhi(iv.y)+r0.w,0.f));
      o.z = pkbf(fmaxf(blo(iv.z)+r1.x,0.f), fmaxf(bhi(iv.z)+r1.y,0.f));
      o.w = pkbf(fmaxf(blo(iv.w)+r1.z,0.f), fmaxf(bhi(iv.w)+r1.w,0.f));
    }
    A_u4[s*8 + (ch ^ (s&7))] = o;
  }
  __syncthreads();

  const int l = tid & 63, w = tid >> 6;
  const int lr = l & 15, g = l >> 4;
  bf16x8 w2f[4][2], a1f[4][2], wwf[4][2];
#pragma unroll
  for(int nt=0; nt<4; ++nt)
#pragma unroll
    for(int kk=0; kk<2; ++kk){
      int d = nt*16 + lr;
      w2f[nt][kk] = *(const bf16x8*)&W2_u4[d*8 + ((kk*4+g) ^ (d&7))];
      a1f[nt][kk] = *(const bf16x8*)&A1_u4[d*8 + ((kk*4+g) ^ (d&7))];
      wwf[nt][kk] = *(const bf16x8*)&WW_u4[d*8 + ((kk*4+g) ^ (d&7))];
    }
  float b2v[4];
#pragma unroll
  for(int nt=0; nt<4; ++nt) b2v[nt] = b2sh[nt*16 + lr];

#pragma unroll
  for(int t=0; t<2; ++t){
    int s = w*32 + t*16 + lr;
    bf16x8 af0 = *(const bf16x8*)&A_u4[s*8 + ((0*4+g) ^ (s&7))];
    bf16x8 af1 = *(const bf16x8*)&A_u4[s*8 + ((1*4+g) ^ (s&7))];
#pragma unroll
    for(int nt=0; nt<4; ++nt){
      f32x4 c0 = { b2v[nt], b2v[nt], b2v[nt], b2v[nt] };
      c0 = __builtin_amdgcn_mfma_f32_16x16x32_bf16(af0, w2f[nt][0], c0, 0, 0, 0);
      c0 = __builtin_amdgcn_mfma_f32_16x16x32_bf16(af1, w2f[nt][1], c0, 0, 0, 0);
      int d = nt*16 + lr;
#pragma unroll
      for(int reg=0; reg<4; ++reg){
        int srow = w*32 + t*16 + g*4 + reg;
        X16[srow*64 + ((d>>3)^(srow&7))*8 + (d&7)] = f2b(fmaxf(c0[reg], 0.f));
      }
    }
    bf16x8 xf0 = *(const bf16x8*)&X_u4[s*8 + ((0*4+g) ^ (s&7))];
    bf16x8 xf1 = *(const bf16x8*)&X_u4[s*8 + ((1*4+g) ^ (s&7))];
#pragma unroll
    for(int nt=0; nt<4; ++nt){
      f32x4 c0 = { 0.f, 0.f, 0.f, 0.f };
      c0 = __builtin_amdgcn_mfma_f32_16x16x32_bf16(xf0, a1f[nt][0], c0, 0, 0, 0);
      c0 = __builtin_amdgcn_mfma_f32_16x16x32_bf16(xf1, a1f[nt][1], c0, 0, 0, 0);
      int d = nt*16 + lr;
#pragma unroll
      for(int reg=0; reg<4; ++reg){
        int srow = w*32 + t*16 + g*4 + reg;
        A16[srow*64 + ((d>>3)^(srow&7))*8 + (d&7)] = f2b(c0[reg]);
      }
    }
#pragma unroll
    for(int nt=0; nt<4; ++nt){
      f32x4 c0 = { 0.f, 0.f, 0.f, 0.f };
      c0 = __builtin_amdgcn_mfma_f32_16x16x32_bf16(xf0, wwf[nt][0], c0, 0, 0, 0);
      c0 = __builtin_amdgcn_mfma_f32_16x16x32_bf16(xf1, wwf[nt][1], c0, 0, 0, 0);
      int d = nt*16 + lr;
#pragma unroll
      for(int reg=0; reg<4; ++reg){
        int srow = w*32 + t*16 + g*4 + reg;
        X16[srow*64 + ((d>>3)^(srow&7))*8 + (d&7)] = f2b(c0[reg]);
      }
    }
  }
  // y_o store (bf16, uint4 chunks)
#pragma unroll
  for(int it=0; it<4; ++it){
    int s = w*32 + it*8 + (l>>3);
    int c2 = l & 7;
    int r = base + s;
    if(r < C_N) y_o[(size_t)r*8 + c2] = X_u4[s*8 + (c2 ^ (s&7))];
  }
  // xa1 store (fp8)
#pragma unroll
  for(int it=0; it<2; ++it){
    int slot = it*64 + l;
    int rl = slot >> 2;
    int c4 = slot & 3;
    int s = w*32 + rl;
    int r = base + s;
    if(r < C_N){
      uint4 h0 = A_u4[s*8 + ((c4*2+0) ^ (s&7))];
      uint4 h1 = A_u4[s*8 + ((c4*2+1) ^ (s&7))];
      uint4 o;
      o.x = ff8(blo(h0.x)) | (ff8(bhi(h0.x))<<8) | (ff8(blo(h0.y))<<16) | (ff8(bhi(h0.y))<<24);
      o.y = ff8(blo(h0.z)) | (ff8(bhi(h0.z))<<8) | (ff8(blo(h0.w))<<16) | (ff8(bhi(h0.w))<<24);
      o.z = ff8(blo(h1.x)) | (ff8(bhi(h1.x))<<8) | (ff8(blo(h1.y))<<16) | (ff8(bhi(h1.y))<<24);
      o.w = ff8(blo(h1.z)) | (ff8(bhi(h1.z))<<8) | (ff8(blo(h1.w))<<16) | (ff8(bhi(h1.w))<<24);
      *(uint4*)(xa1_o8 + (size_t)r*64 + c4*16) = o;
    }
  }
}

// ---------------- MFMA edge-logit kernel: LDS-free, depth-4, pk fp8 decode ----------------
__global__ __launch_bounds__(256) void k_edge_mfma(const unsigned* __restrict__ uc3,
                                                   const int* __restrict__ qbase, const int* __restrict__ blockq,
                                                   const u8* __restrict__ xa1p8, const uint4* __restrict__ userp,
                                                   const u16* __restrict__ w2t_g,
                                                   const float* __restrict__ a2b,
                                                   const float* __restrict__ a3w, const float* __restrict__ a3b,
                                                   float* __restrict__ wlog){
  const int tid = threadIdx.x;
  const int base = blockIdx.x*256;
  const int l = tid & 63, w = tid >> 6;
  const int lr = l & 15;
  const int g  = l >> 4;
  bf16x8 bf[4][2];
#pragma unroll
  for(int nt=0; nt<4; ++nt)
#pragma unroll
    for(int kk=0; kk<2; ++kk){
      int d = nt*16 + lr;
      bf[nt][kk] = *(const bf16x8*)(w2t_g + d*64 + kk*32 + g*8);
    }
  float b2v[4], a3v[4];
#pragma unroll
  for(int nt=0; nt<4; ++nt){ b2v[nt] = a2b[nt*16 + lr]; a3v[nt] = a3w[nt*16 + lr]; }
  const float a3b0 = a3b[0];

  int cin[4], uin[4];
  int bq = blockq[blockIdx.x];
#pragma unroll
  for(int t=0; t<4; ++t){
    int s = base + w*64 + t*16 + lr;
    int sc = (s < E_N) ? s : (E_N-1);
    unsigned vv = (s < E_N) ? uc3[s] : 0u;
    int q = bq;
    while(sc >= qbase[q+1]) ++q;
    cin[t] = (int)(vv & 0x3FFFFu);
    uin[t] = (q<<9) | (int)((vv>>18) & 511u);
  }

  // depth-4: all gather loads in flight
  uint2 xq0[4], xq1[4]; uint4 uv0[4], uv1[4];
#pragma unroll
  for(int t=0; t<4; ++t){
    xq0[t] = *(const uint2*)(xa1p8 + (size_t)cin[t]*64 + g*8);
    xq1[t] = *(const uint2*)(xa1p8 + (size_t)cin[t]*64 + 32 + g*8);
    uv0[t] = userp[(size_t)uin[t]*8 + g];
    uv1[t] = userp[(size_t)uin[t]*8 + 4 + g];
  }

#pragma unroll
  for(int t=0; t<4; ++t){
    union { uint4 u4; bf16x8 v; } a0, a1;
    {
      float2 p01 = f8x2((u16)xq0[t].x), p23 = f8x2((u16)(xq0[t].x>>16));
      float2 p45 = f8x2((u16)xq0[t].y), p67 = f8x2((u16)(xq0[t].y>>16));
      a0.u4.x = pkbf(fmaxf(p01.x+blo(uv0[t].x),0.f), fmaxf(p01.y+bhi(uv0[t].x),0.f));
      a0.u4.y = pkbf(fmaxf(p23.x+blo(uv0[t].y),0.f), fmaxf(p23.y+bhi(uv0[t].y),0.f));
      a0.u4.z = pkbf(fmaxf(p45.x+blo(uv0[t].z),0.f), fmaxf(p45.y+bhi(uv0[t].z),0.f));
      a0.u4.w = pkbf(fmaxf(p67.x+blo(uv0[t].w),0.f), fmaxf(p67.y+bhi(uv0[t].w),0.f));
      p01 = f8x2((u16)xq1[t].x); p23 = f8x2((u16)(xq1[t].x>>16));
      p45 = f8x2((u16)xq1[t].y); p67 = f8x2((u16)(xq1[t].y>>16));
      a1.u4.x = pkbf(fmaxf(p01.x+blo(uv1[t].x),0.f), fmaxf(p01.y+bhi(uv1[t].x),0.f));
      a1.u4.y = pkbf(fmaxf(p23.x+blo(uv1[t].y),0.f), fmaxf(p23.y+bhi(uv1[t].y),0.f));
      a1.u4.z = pkbf(fmaxf(p45.x+blo(uv1[t].z),0.f), fmaxf(p45.y+bhi(uv1[t].z),0.f));
      a1.u4.w = pkbf(fmaxf(p67.x+blo(uv1[t].w),0.f), fmaxf(p67.y+bhi(uv1[t].w),0.f));
    }
    f32x4 acc[4];
#pragma unroll
    for(int nt=0; nt<4; ++nt){
      f32x4 c0 = { b2v[nt], b2v[nt], b2v[nt], b2v[nt] };
      c0 = __builtin_amdgcn_mfma_f32_16x16x32_bf16(a0.v, bf[nt][0], c0, 0, 0, 0);
      c0 = __builtin_amdgcn_mfma_f32_16x16x32_bf16(a1.v, bf[nt][1], c0, 0, 0, 0);
      acc[nt] = c0;
    }
    float s0=0.f, s1=0.f, s2=0.f, s3=0.f;
#pragma unroll
    for(int nt=0; nt<4; ++nt){
      s0 += fmaxf(acc[nt][0], 0.f) * a3v[nt];
      s1 += fmaxf(acc[nt][1], 0.f) * a3v[nt];
      s2 += fmaxf(acc[nt][2], 0.f) * a3v[nt];
      s3 += fmaxf(acc[nt][3], 0.f) * a3v[nt];
    }
#pragma unroll
    for(int mask=1; mask<16; mask<<=1){
      s0 += __shfl_xor(s0, mask);
      s1 += __shfl_xor(s1, mask);
      s2 += __shfl_xor(s2, mask);
      s3 += __shfl_xor(s3, mask);
    }
    if(lr == 0){
      int e0 = base + w*64 + t*16 + g*4;
      if(e0+0 < E_N) wlog[e0+0] = s0 + a3b0;
      if(e0+1 < E_N) wlog[e0+1] = s1 + a3b0;
      if(e0+2 < E_N) wlog[e0+2] = s2 + a3b0;
      if(e0+3 < E_N) wlog[e0+3] = s3 + a3b0;
    }
  }
}

// ---------------- fused softmax (no-max) + MFMA aggregate (bf16 Y, double-buffered) ----------------
__global__ __launch_bounds__(256) void k_aggf(const int* __restrict__ start,
                                              const unsigned* __restrict__ uc3,
                                              const float* __restrict__ wlog,
                                              const u16* __restrict__ Y,
                                              const float* __restrict__ wb,
                                              float* __restrict__ out){
  __shared__ uint4 Ysh[2][4][256];
  int w = threadIdx.x >> 6, l = threadIdx.x & 63;
  int lr = l & 15, g = l >> 4;
  int base = (blockIdx.x*4 + w) * 16;
  if(base >= U_N) return;
  int s0g = start[base];
  int s1g = start[base+16];
  unsigned ml = (unsigned)((base + lr) & 16383);
  int sA = s0g & ~31;
  int nch = (s1g - sA + 31) >> 5;
  const int kb = g*8;

  f32x4 acc[4];
#pragma unroll
  for(int nt=0; nt<4; ++nt) acc[nt] = f32x4{0.f,0.f,0.f,0.f};
  float ssum = 0.f;
  int buf = 0;
  if(nch > 0){
    int rowe = sA + (l>>1);
    int crow = (int)(uc3[rowe] & 0x3FFFFu);
    const uint4* yp = (const uint4*)Y + (size_t)crow*8 + (l&1)*4;
    uint4 y0=yp[0], y1=yp[1], y2=yp[2], y3=yp[3];
    uint4* dst = &Ysh[0][w][(l>>1)*8 + (l&1)*4];
    dst[0]=y0; dst[1]=y1; dst[2]=y2; dst[3]=y3;
  }
  for(int ch=0; ch<nch; ++ch){
    int e0 = sA + ch*32;
    uint4 n0, n1, n2, n3;
    bool hasNext = (ch+1 < nch);
    if(hasNext){
      int rowe = e0 + 32 + (l>>1);
      int crowN = (int)(uc3[rowe] & 0x3FFFFu);
      const uint4* yp = (const uint4*)Y + (size_t)crowN*8 + (l&1)*4;
      n0=yp[0]; n1=yp[1]; n2=yp[2]; n3=yp[3];
    }
    float4 wv0 = *(const float4*)(wlog + e0 + kb);
    float4 wv1 = *(const float4*)(wlog + e0 + kb + 4);
    uint4 v0 = *(const uint4*)(uc3 + e0 + kb);
    uint4 v1 = *(const uint4*)(uc3 + e0 + kb + 4);
    bf16x8 af;
    {
      bool mt; float e;
      mt = ((v0.x>>18)==ml); e = __expf(mt?wv0.x:-1e30f); ssum += e; af[0] = mt?(short)f2b(e):(short)0;
      mt = ((v0.y>>18)==ml); e = __expf(mt?wv0.y:-1e30f); ssum += e; af[1] = mt?(short)f2b(e):(short)0;
      mt = ((v0.z>>18)==ml); e = __expf(mt?wv0.z:-1e30f); ssum += e; af[2] = mt?(short)f2b(e):(short)0;
      mt = ((v0.w>>18)==ml); e = __expf(mt?wv0.w:-1e30f); ssum += e; af[3] = mt?(short)f2b(e):(short)0;
      mt = ((v1.x>>18)==ml); e = __expf(mt?wv1.x:-1e30f); ssum += e; af[4] = mt?(short)f2b(e):(short)0;
      mt = ((v1.y>>18)==ml); e = __expf(mt?wv1.y:-1e30f); ssum += e; af[5] = mt?(short)f2b(e):(short)0;
      mt = ((v1.z>>18)==ml); e = __expf(mt?wv1.z:-1e30f); ssum += e; af[6] = mt?(short)f2b(e):(short)0;
      mt = ((v1.w>>18)==ml); e = __expf(mt?wv1.w:-1e30f); ssum += e; af[7] = mt?(short)f2b(e):(short)0;
    }
    u16* Ysh16 = (u16*)&Ysh[buf][w][0];
    bf16x8 b0, b1, b2, b3;
#pragma unroll
    for(int j=0; j<8; ++j){
      int r = (kb + j)*64 + lr;
      b0[j] = (short)Ysh16[r];
      b1[j] = (short)Ysh16[r+16];
      b2[j] = (short)Ysh16[r+32];
      b3[j] = (short)Ysh16[r+48];
    }
    acc[0] = __builtin_amdgcn_mfma_f32_16x16x32_bf16(af, b0, acc[0], 0, 0, 0);
    acc[1] = __builtin_amdgcn_mfma_f32_16x16x32_bf16(af, b1, acc[1], 0, 0, 0);
    acc[2] = __builtin_amdgcn_mfma_f32_16x16x32_bf16(af, b2, acc[2], 0, 0, 0);
    acc[3] = __builtin_amdgcn_mfma_f32_16x16x32_bf16(af, b3, acc[3], 0, 0, 0);
    if(hasNext){
      uint4* dst = &Ysh[buf^1][w][(l>>1)*8 + (l&1)*4];
      dst[0]=n0; dst[1]=n1; dst[2]=n2; dst[3]=n3;
    }
    buf ^= 1;
  }
  ssum += __shfl_xor(ssum, 16);
  ssum += __shfl_xor(ssum, 32);
  float inv = (ssum > 0.f) ? (1.f/ssum) : 0.f;
  float wbv[4];
#pragma unroll
  for(int nt=0; nt<4; ++nt) wbv[nt] = wb[nt*16 + lr];
#pragma unroll
  for(int reg=0; reg<4; ++reg){
    float sc = __shfl(inv, g*4 + reg);
    int u = base + g*4 + reg;
#pragma unroll
    for(int nt=0; nt<4; ++nt)
      out[(size_t)u*64 + nt*16 + lr] = acc[nt][reg]*sc + wbv[nt];
  }
}

extern "C" void kernel_launch(void* const* d_in, const int* in_sizes, int n_in,
                              void* d_out, int out_size, void* d_ws, size_t ws_size,
                              hipStream_t stream){
  (void)in_sizes; (void)n_in; (void)out_size; (void)ws_size;
  const float4* user_feat  = (const float4*)d_in[0];
  const float4* item_feat  = (const float4*)d_in[1];
  const float*  rating_feat= (const float*)d_in[2];
  const int*    rows       = (const int*)d_in[3];
  const int*    cols       = (const int*)d_in[4];
  const int*    rats       = (const int*)d_in[5];
  const float* gv_w1 = (const float*)d_in[6];
  const float* gv_b1 = (const float*)d_in[7];
  const float* gv_w2 = (const float*)d_in[8];
  const float* gv_b2 = (const float*)d_in[9];
  const float* att_w1= (const float*)d_in[10];
  const float* att_b1= (const float*)d_in[11];
  const float* att_w2= (const float*)d_in[12];
  const float* att_b2= (const float*)d_in[13];
  const float* att_w3= (const float*)d_in[14];
  const float* att_b3= (const float*)d_in[15];
  const float* w_w   = (const float*)d_in[16];
  const float* w_b   = (const float*)d_in[17];
  float* out = (float*)d_out;

  char* ws = (char*)d_ws; size_t off = 0;
  auto take = [&](size_t b)->char*{ char* p = ws + off; off = (off + b + 255) & ~(size_t)255; return p; };
  bf16_t*   item_part  = (bf16_t*)take((size_t)I_N*64*2);
  bf16_t*   user_part  = (bf16_t*)take((size_t)U_N*64*2);
  float*    rating_part= (float*) take((size_t)R_N*64*4);
  bf16_t*   y_t        = (bf16_t*)take((size_t)C_N*64*2);     // 32 MB bf16 (reverted)
  u8*       xa1_8      = (u8*)    take((size_t)C_N*64);       // 16 MB fp8
  float*    wlog_s     = (float*) take((size_t)E_N*4);
  unsigned* uc3        = (unsigned*)take((size_t)E_N*4);
  unsigned* uc2        = (unsigned*)take((size_t)E_N*4);
  int*      hist_g     = (int*)   take((size_t)NBLK_E*NBUCKC*4);
  int*      boff_g     = (int*)   take((size_t)NBLK_E*NBUCKC*4);
  int*      qtot       = (int*)   take((size_t)256*4);
  int*      qbase      = (int*)   take((size_t)256*4);
  int*      blockq     = (int*)   take((size_t)NBLK_E*4);
  int*      start      = (int*)   take((size_t)(NBUCKC*512+64)*4);
  u16*      w1t        = (u16*)   take((size_t)4096*2);
  u16*      u1t        = (u16*)   take((size_t)4096*2);
  u16*      w2t        = (u16*)   take((size_t)4096*2);
  u16*      a1t        = (u16*)   take((size_t)4096*2);
  u16*      a2t        = (u16*)   take((size_t)4096*2);
  u16*      wwt        = (u16*)   take((size_t)4096*2);

  // CSR build
  k_histQ <<<NBLK_E, 256, 0, stream>>>(cols, hist_g);
  k_scanQ <<<NBUCKC, 256, 0, stream>>>(hist_g, boff_g, qtot);
  k_scanT <<<1, 256, 0, stream>>>(qtot, qbase);
  k_blockq<<<(NBLK_E+255)/256, 256, 0, stream>>>(qbase, blockq);
  k_place2<<<NBLK_E, 256, 0, stream>>>(rows, cols, rats, boff_g, qbase, uc2);
  k_fine  <<<NBUCKC, 256, 0, stream>>>(uc2, qbase, uc3, start);
  // weights + tiny GEMV
  k_ratpart <<<1, 320, 0, stream>>>(rating_feat, gv_w1, gv_b1, rating_part);
  k_prepw6  <<<96, 256, 0, stream>>>(gv_w1, att_w1, gv_w2, att_w2, w_w, w1t, u1t, w2t, a1t, a2t, wwt);
  // dense precompute (MFMA)
  k_rowgemm<false><<<(I_N+255)/256, 256, 0, stream>>>(item_feat, (const uint4*)w1t, nullptr,
                                                      (uint4*)item_part, I_N);
  k_rowgemm<true> <<<(U_N+255)/256, 256, 0, stream>>>(user_feat, (const uint4*)u1t, att_b1,
                                                      (uint4*)user_part, U_N);
  k_combo_mfma<<<NBLK_C, 256, 0, stream>>>((const uint4*)item_part, (const float4*)rating_part,
                                           (const uint4*)w2t, (const uint4*)a1t, (const uint4*)wwt, gv_b2,
                                           (uint4*)y_t, xa1_8);
  // per-edge logits
  k_edge_mfma<<<NBLK_E, 256, 0, stream>>>(uc3, qbase, blockq, xa1_8, (const uint4*)user_part,
                                          w2t, att_b2, att_w3, att_b3, wlog_s);
  // fused softmax + aggregate + projection
  k_aggf <<<(U_N/64)+1, 256, 0, stream>>>(start, uc3, wlog_s, (const u16*)y_t, w_b, out);
}